// Round 5
// baseline (228.650 us; speedup 1.0000x reference)
//
#include <hip/hip_runtime.h>
#include <math.h>

typedef short bf16x8 __attribute__((ext_vector_type(8)));
typedef short bf16x4 __attribute__((ext_vector_type(4)));
typedef float f32x4  __attribute__((ext_vector_type(4)));

#define INV_2PI  0.15915494309189535f
#define TWO_PI_F 6.283185307179586f
// DT/(2*pi)/N = 0.01/(2*pi)/192
#define FSCALE   8.2893199e-06f

static __device__ inline short f2bf(float f) {
    union { float f; unsigned u; } v; v.f = f;
    unsigned r = (v.u + 0x7FFFu + ((v.u >> 16) & 1u)) >> 16;
    return (short)r;
}
static __device__ inline float bf2f(short h) {
    union { unsigned u; float f; } v; v.u = ((unsigned)(unsigned short)h) << 16;
    return v.f;
}
static __device__ inline bf16x8 cvt8(float4 u, float4 v) {
    bf16x8 h;
    h[0] = f2bf(u.x); h[1] = f2bf(u.y); h[2] = f2bf(u.z); h[3] = f2bf(u.w);
    h[4] = f2bf(v.x); h[5] = f2bf(v.y); h[6] = f2bf(v.z); h[7] = f2bf(v.w);
    return h;
}

// ============================ K1: fused main ============================
// [0,576):    phase split-K partials fp32. Dbuf LDS (8 barriers), depth-2 reg
//             prefetch, no global stores in K-loop. Bit-identical MAC order.
//             On finish: threadfence + atomicAdd(ctr[rb]).
// [576,960):  encode GEMM bf16 MFMA 64x64 from fp32 x/Wf (in-reg cvt,
//             bit-identical to XB path). Independent of phase.
// [960,972):  Wfu fp32->bf16 into WB (for back kernel).
// [972,1100): kuramoto (16 rows/block). Builds K-frags from IC + om/bp from
//             raw inputs BEFORE spinning on its 18 producers (ctr[g>>2]==18),
//             then acquire-fence, coalesced gather, 10-step chain.
__global__ __launch_bounds__(256) void main_kernel(
    const float* __restrict__ xa, const float* __restrict__ xt, const float* __restrict__ xv,
    const float* __restrict__ Wpa, const float* __restrict__ Wpt, const float* __restrict__ Wpv,
    const float* __restrict__ Wfa, const float* __restrict__ Wft, const float* __restrict__ Wfv,
    const float* __restrict__ bfa, const float* __restrict__ bft, const float* __restrict__ bfv,
    const float* __restrict__ Wfu, const float* __restrict__ IC,
    const float* __restrict__ oa, const float* __restrict__ ot, const float* __restrict__ ov,
    const float* __restrict__ bpa, const float* __restrict__ bpt, const float* __restrict__ bpv,
    float* __restrict__ partial, short* __restrict__ e_bf16, short* __restrict__ WB,
    float* __restrict__ phases_out, float* __restrict__ pm,
    float* __restrict__ bacc_part, unsigned* __restrict__ ctr)
{
    __shared__ alignas(16) char smem[27840];
    int b = blockIdx.x;
    int t = threadIdx.x;
    int lane = t & 63, w = t >> 6;
    int q = lane >> 4, col = lane & 15;

    if (b < 576) {
        // ---------- phase partial (dbuf, 8 barriers) ----------
        float (*As)[16][72] = (float (*)[16][72])smem;
        float (*Bs)[16][72] = (float (*)[16][72])(smem + 9216);
        int slot = b % 18, rb = b / 18;
        int z = slot < 4 ? 0 : (slot < 10 ? 1 : 2);
        int chunk = slot - (z == 0 ? 0 : (z == 1 ? 4 : 10));
        const float* A = z == 0 ? xa : (z == 1 ? xt : xv);
        const float* W = z == 0 ? Wpa : (z == 1 ? Wpt : Wpv);
        int K = z == 0 ? 512 : (z == 1 ? 768 : 1024);
        int kb = chunk * 128;
        int m0 = rb * 64;

        int tx = t & 15, ty = t >> 4;
        int row = t >> 2, c4 = t & 3;

        float acc[4][4] = {};
        float4 arq[2], brq[2];
        arq[0] = *(const float4*)&A[(size_t)(m0 + row) * K + kb + c4 * 4];
        brq[0] = *(const float4*)&W[(size_t)row * K + kb + c4 * 4];
        arq[1] = *(const float4*)&A[(size_t)(m0 + row) * K + kb + 16 + c4 * 4];
        brq[1] = *(const float4*)&W[(size_t)row * K + kb + 16 + c4 * 4];

        for (int it = 0; it < 8; ++it) {
            int cur = it & 1;
            As[cur][c4 * 4 + 0][row] = arq[cur].x;
            As[cur][c4 * 4 + 1][row] = arq[cur].y;
            As[cur][c4 * 4 + 2][row] = arq[cur].z;
            As[cur][c4 * 4 + 3][row] = arq[cur].w;
            Bs[cur][c4 * 4 + 0][row] = brq[cur].x;
            Bs[cur][c4 * 4 + 1][row] = brq[cur].y;
            Bs[cur][c4 * 4 + 2][row] = brq[cur].z;
            Bs[cur][c4 * 4 + 3][row] = brq[cur].w;
            __syncthreads();
            if (it + 2 < 8) {
                arq[cur] = *(const float4*)&A[(size_t)(m0 + row) * K + kb + (it + 2) * 16 + c4 * 4];
                brq[cur] = *(const float4*)&W[(size_t)row * K + kb + (it + 2) * 16 + c4 * 4];
            }
#pragma unroll
            for (int kk = 0; kk < 16; ++kk) {
                float4 aq = *(const float4*)&As[cur][kk][ty * 4];
                float4 bq = *(const float4*)&Bs[cur][kk][tx * 4];
                float av[4] = {aq.x, aq.y, aq.z, aq.w};
                float bv[4] = {bq.x, bq.y, bq.z, bq.w};
#pragma unroll
                for (int i = 0; i < 4; ++i)
#pragma unroll
                    for (int j = 0; j < 4; ++j)
                        acc[i][j] += av[i] * bv[j];
            }
        }

        // store: chunk-contiguous layout [qb][slot][16][64]
#pragma unroll
        for (int i = 0; i < 4; ++i) {
            int row_l = ty * 4 + i;
            int qb = rb * 4 + (row_l >> 4), rloc = row_l & 15;
            float4 v = make_float4(acc[i][0], acc[i][1], acc[i][2], acc[i][3]);
            *(float4*)&partial[((size_t)(qb * 18 + slot)) * 1024 + rloc * 64 + tx * 4] = v;
        }
        __threadfence();                 // release per-thread stores (device scope)
        __syncthreads();                 // all threads fenced
        if (t == 0) atomicAdd(&ctr[rb], 1u);
    } else if (b < 960) {
        // ---------- encode GEMM (fp32 inputs, in-register bf16 convert) ----------
        int bb = b - 576;
        int z = bb >> 7, r = bb & 127;
        int m0 = (r >> 2) * 64, n0 = (r & 3) * 64;
        const float* A    = z == 0 ? xa : (z == 1 ? xt : xv);
        const float* Wf   = z == 0 ? Wfa : (z == 1 ? Wft : Wfv);
        const float* bias = z == 0 ? bfa : (z == 1 ? bft : bfv);
        int K             = z == 0 ? 512 : (z == 1 ? 768 : 1024);

        short* As = (short*)smem;            // [64][72]
        short* Bs = (short*)smem + 64 * 72;

        int srow = t >> 3, sc8 = t & 7;      // 32 rows x 8 groups per pass

        f32x4 acc[4];
#pragma unroll
        for (int f = 0; f < 4; ++f)
#pragma unroll
            for (int rr = 0; rr < 4; ++rr) acc[f][rr] = 0.f;

        float4 a0[2], a1[2], b0[2], b1[2];
#pragma unroll
        for (int p = 0; p < 2; ++p) {
            int rw = srow + 32 * p;
            a0[p] = *(const float4*)&A[(size_t)(m0 + rw) * K + sc8 * 8];
            a1[p] = *(const float4*)&A[(size_t)(m0 + rw) * K + sc8 * 8 + 4];
            b0[p] = *(const float4*)&Wf[(size_t)(n0 + rw) * K + sc8 * 8];
            b1[p] = *(const float4*)&Wf[(size_t)(n0 + rw) * K + sc8 * 8 + 4];
        }

        for (int kb = 0; kb < K; kb += 64) {
            if (kb) __syncthreads();
#pragma unroll
            for (int p = 0; p < 2; ++p) {
                int rw = srow + 32 * p;
                *(bf16x8*)&As[rw * 72 + sc8 * 8] = cvt8(a0[p], a1[p]);
                *(bf16x8*)&Bs[rw * 72 + sc8 * 8] = cvt8(b0[p], b1[p]);
            }
            __syncthreads();
            if (kb + 64 < K) {
                int k = kb + 64;
#pragma unroll
                for (int p = 0; p < 2; ++p) {
                    int rw = srow + 32 * p;
                    a0[p] = *(const float4*)&A[(size_t)(m0 + rw) * K + k + sc8 * 8];
                    a1[p] = *(const float4*)&A[(size_t)(m0 + rw) * K + k + sc8 * 8 + 4];
                    b0[p] = *(const float4*)&Wf[(size_t)(n0 + rw) * K + k + sc8 * 8];
                    b1[p] = *(const float4*)&Wf[(size_t)(n0 + rw) * K + k + sc8 * 8 + 4];
                }
            }

            bf16x8 bfr[2];
#pragma unroll
            for (int kc = 0; kc < 2; ++kc)
                bfr[kc] = *(const bf16x8*)&Bs[(w * 16 + col) * 72 + kc * 32 + q * 8];
#pragma unroll
            for (int f = 0; f < 4; ++f)
#pragma unroll
                for (int kc = 0; kc < 2; ++kc) {
                    bf16x8 af = *(const bf16x8*)&As[(f * 16 + col) * 72 + kc * 32 + q * 8];
                    acc[f] = __builtin_amdgcn_mfma_f32_16x16x32_bf16(af, bfr[kc], acc[f], 0, 0, 0);
                }
        }

        int n = n0 + w * 16 + col;
        float bn = bias[n];
#pragma unroll
        for (int f = 0; f < 4; ++f)
#pragma unroll
            for (int rr = 0; rr < 4; ++rr) {
                int m = m0 + f * 16 + q * 4 + rr;
                e_bf16[(size_t)m * 768 + z * 256 + n] = f2bf(acc[f][rr] + bn);
            }
    } else if (b < 972) {
        // ---------- Wfu fp32->bf16 (49152 float4 units) ----------
        for (int u = (b - 960) * 256 + t; u < 49152; u += 12 * 256) {
            float4 v = ((const float4*)Wfu)[u];
            bf16x4 h; h[0] = f2bf(v.x); h[1] = f2bf(v.y); h[2] = f2bf(v.z); h[3] = f2bf(v.w);
            *(bf16x4*)(WB + (size_t)u * 4) = h;
        }
    } else {
        // ---------- kuramoto ----------
        short (*cs)[2][16][216] = (short (*)[2][16][216])smem;      // 27648 B
        float (*Rl)[3] = (float (*)[3])(smem + 27648);              // 192 B
        float* ph0 = (float*)smem;                                  // [16][196] overlay

        int g = b - 972;
        int m0 = g * 16;

        // K-frags straight from IC (bit-identical to the old packed path);
        // runs BEFORE the spin, overlapped with producers.
        bf16x8 kb_[3][6];
#pragma unroll
        for (int ntl = 0; ntl < 3; ++ntl)
#pragma unroll
            for (int kc = 0; kc < 6; ++kc) {
                int nt = w * 3 + ntl;
                int n = nt * 16 + (lane & 15);
                int kbase = kc * 32 + (lane >> 4) * 8;
#pragma unroll
                for (int j = 0; j < 8; ++j) {
                    int k = kbase + j;
                    float v = 0.5f * (IC[k * 192 + n] + IC[n * 192 + k]);
                    kb_[ntl][kc][j] = f2bf(v);
                }
            }

        // om/bp inline from raw inputs (bit-identical values)
        float om[3], bpv_[3];
#pragma unroll
        for (int ntl = 0; ntl < 3; ++ntl) {
            int i = (w * 3 + ntl) * 16 + col;
            int z = i >> 6, ii = i & 63;
            float wv = z == 0 ? oa[ii] : (z == 1 ? ot[ii] : ov[ii]);
            om[ntl] = wv * (0.01f * INV_2PI);
            bpv_[ntl] = z == 0 ? bpa[ii] : (z == 1 ? bpt[ii] : bpv[ii]);
        }

        // spin on the 18 producers of this row-block
        if (t == 0) {
            while (atomicAdd(&ctr[g >> 2], 0u) < 18u) __builtin_amdgcn_s_sleep(2);
        }
        __syncthreads();
        __threadfence();                 // acquire

        // ---- init gather: 18 coalesced b128 loads, reduce per modality ----
        {
            const float* Pb = partial + (size_t)g * 18 * 1024;
            f32x4 s0, s1, s2;
#pragma unroll
            for (int j = 0; j < 4; ++j) { s0[j] = 0.f; s1[j] = 0.f; s2[j] = 0.f; }
#pragma unroll
            for (int s = 0; s < 18; ++s) {
                f32x4 v = *(const f32x4*)&Pb[s * 1024 + t * 4];
                if (s < 4)       s0 += v;
                else if (s < 10) s1 += v;
                else             s2 += v;
            }
            int row = t >> 4, c4 = t & 15;
            *(f32x4*)&ph0[row * 196 +   0 + c4 * 4] = s0;
            *(f32x4*)&ph0[row * 196 +  64 + c4 * 4] = s1;
            *(f32x4*)&ph0[row * 196 + 128 + c4 * 4] = s2;
        }
        __syncthreads();

        float ph[3][4], c[3][4], s[3][4];
#pragma unroll
        for (int ntl = 0; ntl < 3; ++ntl) {
            int i = (w * 3 + ntl) * 16 + col;
#pragma unroll
            for (int r = 0; r < 4; ++r) {
                float raw = bpv_[ntl] + ph0[(q * 4 + r) * 196 + i];
                raw *= INV_2PI;
                ph[ntl][r] = raw - floorf(raw);
            }
        }
        __syncthreads();   // ph0 region reused as cs below

        for (int step = 0; step < 10; ++step) {
            int p = step & 1;
#pragma unroll
            for (int ntl = 0; ntl < 3; ++ntl) {
                int i = (w * 3 + ntl) * 16 + col;
#pragma unroll
                for (int r = 0; r < 4; ++r) {
                    c[ntl][r] = __builtin_amdgcn_cosf(ph[ntl][r]);  // v_cos_f32: revolutions
                    s[ntl][r] = __builtin_amdgcn_sinf(ph[ntl][r]);
                    cs[p][0][q * 4 + r][i] = f2bf(c[ntl][r]);
                    cs[p][1][q * 4 + r][i] = f2bf(s[ntl][r]);
                }
            }
            __syncthreads();
            // (2nd per-step barrier elided: cs double-buffered)

            f32x4 aC[3], aS[3];
#pragma unroll
            for (int ntl = 0; ntl < 3; ++ntl)
#pragma unroll
                for (int r = 0; r < 4; ++r) { aC[ntl][r] = 0.f; aS[ntl][r] = 0.f; }

#pragma unroll
            for (int kc = 0; kc < 6; ++kc) {
                bf16x8 ac  = *(const bf16x8*)&cs[p][0][col][kc * 32 + q * 8];
                bf16x8 as_ = *(const bf16x8*)&cs[p][1][col][kc * 32 + q * 8];
#pragma unroll
                for (int ntl = 0; ntl < 3; ++ntl) {
                    aC[ntl] = __builtin_amdgcn_mfma_f32_16x16x32_bf16(ac,  kb_[ntl][kc], aC[ntl], 0, 0, 0);
                    aS[ntl] = __builtin_amdgcn_mfma_f32_16x16x32_bf16(as_, kb_[ntl][kc], aS[ntl], 0, 0, 0);
                }
            }

#pragma unroll
            for (int ntl = 0; ntl < 3; ++ntl)
#pragma unroll
                for (int r = 0; r < 4; ++r) {
                    float f = (s[ntl][r] * aC[ntl][r] - c[ntl][r] * aS[ntl][r]) * FSCALE;
                    float pn = ph[ntl][r] + om[ntl] + f;
                    ph[ntl][r] = pn - floorf(pn);
                }
        }

#pragma unroll
        for (int ntl = 0; ntl < 3; ++ntl) {
            int i = (w * 3 + ntl) * 16 + col;
#pragma unroll
            for (int r = 0; r < 4; ++r) {
                float cp = __builtin_amdgcn_cosf(ph[ntl][r]);
                float sp = __builtin_amdgcn_sinf(ph[ntl][r]);
                cs[0][0][q * 4 + r][i] = f2bf(cp);
                cs[0][1][q * 4 + r][i] = f2bf(sp);
                phases_out[(size_t)(m0 + q * 4 + r) * 192 + i] = ph[ntl][r] * TWO_PI_F;
            }
        }
        __syncthreads();

        if (t < 48) {
            int r = t & 15, mod = t >> 4;
            float sc = 0.f, ss = 0.f;
#pragma unroll
            for (int gg = 0; gg < 8; ++gg) {
                bf16x8 vc = *(const bf16x8*)&cs[0][0][r][mod * 64 + gg * 8];
                bf16x8 vs = *(const bf16x8*)&cs[0][1][r][mod * 64 + gg * 8];
#pragma unroll
                for (int j = 0; j < 8; ++j) { sc += bf2f(vc[j]); ss += bf2f(vs[j]); }
            }
            sc *= (1.f / 64.f); ss *= (1.f / 64.f);
            pm[(size_t)(m0 + r) * 3 + mod] = 0.5f + 0.5f * sc;
            Rl[r][mod] = sqrtf(sc * sc + ss * ss);
        }
        __syncthreads();
        if (t < 3) {
            int a = (t == 2) ? 1 : 0;
            int bb2 = (t == 0) ? 1 : 2;
            float accp = 0.f;
            for (int r = 0; r < 16; ++r) accp += Rl[r][a] * Rl[r][bb2];
            bacc_part[g * 4 + t] = accp;     // per-block slot, no atomic
        }
    }
}

// ============================ K2: fusion + finalize ============================
// bound = (e * pm_scale) @ Wfu^T + b_fusion. Grid (128,2): 16 rows x 128 cols
// per block. A staged+scaled in LDS once; barrier-free K-loop, reg-dbuf B.
__global__ __launch_bounds__(256) void back_kernel(
    const short* __restrict__ e_bf16, const short* __restrict__ WB,
    const float* __restrict__ bias, const float* __restrict__ pm,
    const float* __restrict__ bacc_part,
    float* __restrict__ out_bound, float* __restrict__ out_bm, float* __restrict__ out_total)
{
    const short* Wfb = WB;   // Wfu slab (bf16)
    __shared__ alignas(16) short As2[16 * 776];   // 24832 B
    __shared__ float fsum[3];

    int m0 = blockIdx.x * 16, n0 = blockIdx.y * 128;
    int t = threadIdx.x;
    int lane = t & 63, w = t >> 6;
    int q = lane >> 4, col = lane & 15;

#pragma unroll
    for (int i = 0; i < 6; ++i) {
        int g = t + 256 * i;                 // < 1536
        int rw = g / 96, cg = g - rw * 96;
        float sc = pm[(size_t)(m0 + rw) * 3 + (cg >> 5)];
        bf16x8 v = *(const bf16x8*)&e_bf16[(size_t)(m0 + rw) * 768 + cg * 8];
        bf16x8 h;
#pragma unroll
        for (int j = 0; j < 8; ++j) h[j] = f2bf(bf2f(v[j]) * sc);
        *(bf16x8*)&As2[rw * 776 + cg * 8] = h;
    }
    __syncthreads();

    f32x4 facc[2];
#pragma unroll
    for (int j = 0; j < 2; ++j)
#pragma unroll
        for (int rr = 0; rr < 4; ++rr) facc[j][rr] = 0.f;

    int n_[2];
#pragma unroll
    for (int j = 0; j < 2; ++j) n_[j] = n0 + (w * 2 + j) * 16 + col;

    bf16x8 bcur[2], bnxt[2];
#pragma unroll
    for (int j = 0; j < 2; ++j)
        bcur[j] = *(const bf16x8*)&Wfb[(size_t)n_[j] * 768 + q * 8];

    for (int k0 = 0; k0 < 768; k0 += 32) {
        if (k0 + 32 < 768) {
#pragma unroll
            for (int j = 0; j < 2; ++j)
                bnxt[j] = *(const bf16x8*)&Wfb[(size_t)n_[j] * 768 + k0 + 32 + q * 8];
        }
        bf16x8 af = *(const bf16x8*)&As2[col * 776 + k0 + q * 8];
#pragma unroll
        for (int j = 0; j < 2; ++j)
            facc[j] = __builtin_amdgcn_mfma_f32_16x16x32_bf16(af, bcur[j], facc[j], 0, 0, 0);
#pragma unroll
        for (int j = 0; j < 2; ++j) bcur[j] = bnxt[j];
    }

#pragma unroll
    for (int j = 0; j < 2; ++j) {
        float bn = bias[n_[j]];
#pragma unroll
        for (int rr = 0; rr < 4; ++rr) {
            int m = m0 + q * 4 + rr;
            out_bound[(size_t)m * 256 + n_[j]] = facc[j][rr] + bn;
        }
    }

    if (blockIdx.x == 0 && blockIdx.y == 0) {
        if (t < 3) {
            float s = 0.f;
            for (int g = 0; g < 128; ++g) s += bacc_part[g * 4 + t];
            fsum[t] = s;
        }
        __syncthreads();
        float p01 = fsum[0] * (1.f / 2048.f);
        float p02 = fsum[1] * (1.f / 2048.f);
        float p12 = fsum[2] * (1.f / 2048.f);
        float total = (p01 + p02 + p12) * (1.f / 3.f);
        if (t == 0) {
            out_bm[0] = 1.f; out_bm[1] = p01; out_bm[2] = p02;
            out_bm[3] = p01; out_bm[4] = 1.f; out_bm[5] = p12;
            out_bm[6] = p02; out_bm[7] = p12; out_bm[8] = 1.f;
        }
        for (int i = t; i < 2048; i += 256) out_total[i] = total;
    }
}

// ============================ launch ============================
extern "C" void kernel_launch(void* const* d_in, const int* in_sizes, int n_in,
                              void* d_out, int out_size, void* d_ws, size_t ws_size,
                              hipStream_t stream)
{
    const float* x_a  = (const float*)d_in[0];
    const float* Wf_a = (const float*)d_in[1];
    const float* bf_a = (const float*)d_in[2];
    const float* Wp_a = (const float*)d_in[3];
    const float* bp_a = (const float*)d_in[4];
    const float* x_t  = (const float*)d_in[5];
    const float* Wf_t = (const float*)d_in[6];
    const float* bf_t = (const float*)d_in[7];
    const float* Wp_t = (const float*)d_in[8];
    const float* bp_t = (const float*)d_in[9];
    const float* x_v  = (const float*)d_in[10];
    const float* Wf_v = (const float*)d_in[11];
    const float* bf_v = (const float*)d_in[12];
    const float* Wp_v = (const float*)d_in[13];
    const float* bp_v = (const float*)d_in[14];
    const float* om_a = (const float*)d_in[15];
    const float* om_t = (const float*)d_in[16];
    const float* om_v = (const float*)d_in[17];
    const float* IC   = (const float*)d_in[18];
    const float* Wfu  = (const float*)d_in[19];
    const float* bfu  = (const float*)d_in[20];

    float* ws        = (float*)d_ws;
    unsigned* ctrw   = (unsigned*)ws;           // 32 uints  [0,32)
    float* baccp     = ws + 32;                 // 512       [32,544)
    float* pmv       = ws + 544;                // 6144      [544,6688)
    float* partial   = ws + 6688;               // 2359296   [6688,2365984)
    short* e_bf      = (short*)(ws + 2365984);  // 1572864 shorts
    short* WB        = (short*)(ws + 3152416);  // 196608 shorts (Wfu bf16)

    float* out        = (float*)d_out;
    float* out_bound  = out;           // 2048*256
    float* out_bm     = out + 524288;  // 9
    float* out_phases = out + 524297;  // 2048*192
    float* out_total  = out + 917513;  // 2048

    hipMemsetAsync(ctrw, 0, 128, stream);   // zero the 32 producer counters

    main_kernel<<<1100, 256, 0, stream>>>(
        x_a, x_t, x_v, Wp_a, Wp_t, Wp_v, Wf_a, Wf_t, Wf_v,
        bf_a, bf_t, bf_v, Wfu, IC, om_a, om_t, om_v, bp_a, bp_t, bp_v,
        partial, e_bf, WB, out_phases, pmv, baccp, ctrw);

    dim3 gF(128, 2);
    back_kernel<<<gF, 256, 0, stream>>>(e_bf, WB, bfu, pmv, baccp,
                                        out_bound, out_bm, out_total);
}